// Round 7
// baseline (252.169 us; speedup 1.0000x reference)
//
#include <hip/hip_runtime.h>

typedef _Float16 half8 __attribute__((ext_vector_type(8)));
typedef float floatx4 __attribute__((ext_vector_type(4)));
typedef float float4v __attribute__((ext_vector_type(4)));

#define DIM   768
#define NROW  196
#define AUNITS (64 * 13 * 24 * 64)    // 16B units in A'' (fragment-tiled image)
#define TUNITS (64 * 4 * 24 * 64)     // 16B units in B'' (fragment-tiled text)
#define A_HALFS ((size_t)AUNITS * 8)
#define BJ_HALFS (24 * 4 * 64 * 8)    // 49152 halfs per j

// ---------- repack: f32 -> f16 into MFMA-fragment-tiled layout ----------
// A''[i][tau][s][lane]{8}: lane l holds A_i[n=tau*16+(l&15)][d=s*32+(l>>4)*8..+7]
// B''[j][s][ct][lane]{8}:  lane l holds B_j[m=ct*16+(l&15)][d=s*32+(l>>4)*8..+7]
__global__ __launch_bounds__(256) void repack(const float* __restrict__ img,
                                              const float* __restrict__ txt,
                                              _Float16* __restrict__ Apk,
                                              _Float16* __restrict__ Bpk) {
  int gid = blockIdx.x * 256 + threadIdx.x;
  const float* src;
  _Float16* dst;
  if (gid < AUNITS) {
    int l = gid & 63, g = gid >> 6;
    int s = g % 24; g /= 24;
    int tau = g % 13; int i = g / 13;
    int n = tau * 16 + (l & 15); if (n > 195) n = 195;   // dup-pad rows 196..207
    src = img + (size_t)i * 197 * 768 + (size_t)(n + 1) * 768 + s * 32 + (l >> 4) * 8;
    dst = Apk + (size_t)gid * 8;
  } else {
    int u = gid - AUNITS;
    int l = u & 63, g = u >> 6;
    int ct = g & 3; g >>= 2;
    int s = g % 24; int j = g / 24;
    int m = ct * 16 + (l & 15);
    src = txt + (size_t)j * 65 * 768 + (size_t)(m + 1) * 768 + s * 32 + (l >> 4) * 8;
    dst = Bpk + (size_t)u * 8;
  }
  float4v v0 = *(const float4v*)src;
  float4v v1 = *(const float4v*)(src + 4);
  half8 h;
  h[0] = (_Float16)v0[0]; h[1] = (_Float16)v0[1]; h[2] = (_Float16)v0[2]; h[3] = (_Float16)v0[3];
  h[4] = (_Float16)v1[0]; h[5] = (_Float16)v1[1]; h[6] = (_Float16)v1[2]; h[7] = (_Float16)v1[3];
  *(half8*)dst = h;
}

// ---------- per-(i,j): fully register-streamed, ZERO K-loop barriers ----------
// 4 waves; wave w owns row tiles {w, w+4, w+8} plus column-group w of tile 12.
// A and B fragments both loaded per-wave from global (L2/L1); B's 4x intra-block
// re-read is served by L1 (all waves touch the same 4KB/K-step nearly in lockstep).
__global__ __launch_bounds__(256, 3) void sim_kernel(const _Float16* __restrict__ Apk,
                                                     const _Float16* __restrict__ Bpk,
                                                     const int* __restrict__ pm,
                                                     const float* __restrict__ ls,
                                                     float* __restrict__ lpi,
                                                     float* __restrict__ lpt) {
  __shared__ float colmaxLDS[4][64];
  __shared__ float t12buf[4][64];
  __shared__ float wsumLDS[4];

  const int j = blockIdx.x, i = blockIdx.y;
  const int tid = threadIdx.x;
  const int wave = tid >> 6, lane = tid & 63;
  const int r16 = lane & 15;
  const int lane8 = lane * 8;

  const _Float16* Ai = Apk + (size_t)i * 13 * 24 * 512;
  const _Float16* pA[4];
  pA[0] = Ai + (size_t)(wave)     * 24 * 512 + lane8;
  pA[1] = Ai + (size_t)(wave + 4) * 24 * 512 + lane8;
  pA[2] = Ai + (size_t)(wave + 8) * 24 * 512 + lane8;
  pA[3] = Ai + (size_t)12         * 24 * 512 + lane8;   // tile 12 (all waves, L1-shared)
  const _Float16* pB = Bpk + (size_t)j * BJ_HALFS + lane8;
  // per-K-step strides: A +512 halfs (1024B), B +2048 halfs (4096B); col-group ct at +ct*512

  // register pipeline, depth 2: 4 A-frags + 4 B-frags per step
  half8 af[2][4], bf[2][4];
#pragma unroll
  for (int d = 0; d < 2; ++d) {
#pragma unroll
    for (int t = 0; t < 4; ++t)
      af[d][t] = *(const half8*)(pA[t] + d * 512);
#pragma unroll
    for (int cc = 0; cc < 4; ++cc) {
      int ct = (wave + cc) & 3;             // rotated: bf[*][0] is this wave's own group
      bf[d][cc] = *(const half8*)(pB + d * 2048 + ct * 512);
    }
  }

  floatx4 acc[3][4];
  floatx4 acc12 = (floatx4){0.f, 0.f, 0.f, 0.f};
#pragma unroll
  for (int t = 0; t < 3; ++t)
#pragma unroll
    for (int cc = 0; cc < 4; ++cc)
      acc[t][cc] = (floatx4){0.f, 0.f, 0.f, 0.f};

#pragma unroll
  for (int s = 0; s < 24; ++s) {
    half8 a0 = af[s & 1][0], a1 = af[s & 1][1], a2 = af[s & 1][2], a3 = af[s & 1][3];
    half8 b0 = bf[s & 1][0], b1 = bf[s & 1][1], b2 = bf[s & 1][2], b3 = bf[s & 1][3];
    if (s < 22) {                           // prefetch K-step s+2 (compile-time guard)
#pragma unroll
      for (int t = 0; t < 4; ++t)
        af[s & 1][t] = *(const half8*)(pA[t] + (s + 2) * 512);
#pragma unroll
      for (int cc = 0; cc < 4; ++cc) {
        int ct = (wave + cc) & 3;
        bf[s & 1][cc] = *(const half8*)(pB + (s + 2) * 2048 + ct * 512);
      }
    }
    acc[0][0] = __builtin_amdgcn_mfma_f32_16x16x32_f16(a0, b0, acc[0][0], 0, 0, 0);
    acc[1][0] = __builtin_amdgcn_mfma_f32_16x16x32_f16(a1, b0, acc[1][0], 0, 0, 0);
    acc[2][0] = __builtin_amdgcn_mfma_f32_16x16x32_f16(a2, b0, acc[2][0], 0, 0, 0);
    acc12     = __builtin_amdgcn_mfma_f32_16x16x32_f16(a3, b0, acc12,     0, 0, 0);
    acc[0][1] = __builtin_amdgcn_mfma_f32_16x16x32_f16(a0, b1, acc[0][1], 0, 0, 0);
    acc[1][1] = __builtin_amdgcn_mfma_f32_16x16x32_f16(a1, b1, acc[1][1], 0, 0, 0);
    acc[2][1] = __builtin_amdgcn_mfma_f32_16x16x32_f16(a2, b1, acc[2][1], 0, 0, 0);
    acc[0][2] = __builtin_amdgcn_mfma_f32_16x16x32_f16(a0, b2, acc[0][2], 0, 0, 0);
    acc[1][2] = __builtin_amdgcn_mfma_f32_16x16x32_f16(a1, b2, acc[1][2], 0, 0, 0);
    acc[2][2] = __builtin_amdgcn_mfma_f32_16x16x32_f16(a2, b2, acc[2][2], 0, 0, 0);
    acc[0][3] = __builtin_amdgcn_mfma_f32_16x16x32_f16(a0, b3, acc[0][3], 0, 0, 0);
    acc[1][3] = __builtin_amdgcn_mfma_f32_16x16x32_f16(a1, b3, acc[1][3], 0, 0, 0);
    acc[2][3] = __builtin_amdgcn_mfma_f32_16x16x32_f16(a2, b3, acc[2][3], 0, 0, 0);
  }

  // ---------------- epilogue ----------------
  const float sgl = ls[0];
  // mask depends on i only (reference broadcasts pm over i, not j)
  bool msk[4];
  int colc[4];
#pragma unroll
  for (int cc = 0; cc < 4; ++cc) {
    colc[cc] = ((wave + cc) & 3) * 16 + r16;
    msk[cc] = pm[i * 65 + 1 + colc[cc]] != 0;
  }

  // rows 0..191 row-max over valid m (each row counted by 16 r16-lanes)
  float rowsum = 0.f;
#pragma unroll
  for (int t = 0; t < 3; ++t) {
#pragma unroll
    for (int r = 0; r < 4; ++r) {
      float rm = -__builtin_inff();
#pragma unroll
      for (int cc = 0; cc < 4; ++cc) {
        float v = acc[t][cc][r] * sgl;
        rm = fmaxf(rm, msk[cc] ? -__builtin_inff() : v);
      }
#pragma unroll
      for (int off = 1; off < 16; off <<= 1)
        rm = fmaxf(rm, __shfl_xor(rm, off, 64));
      rowsum += rm;
    }
  }
#pragma unroll
  for (int off = 1; off < 64; off <<= 1) rowsum += __shfl_xor(rowsum, off, 64);

  // per-column max over rows 0..191 (unmasked, per reference max_n)
  float cmv[4];
#pragma unroll
  for (int cc = 0; cc < 4; ++cc) {
    float cm = -__builtin_inff();
#pragma unroll
    for (int t = 0; t < 3; ++t)
#pragma unroll
      for (int r = 0; r < 4; ++r)
        cm = fmaxf(cm, acc[t][cc][r] * sgl);
    cm = fmaxf(cm, __shfl_xor(cm, 16, 64));
    cm = fmaxf(cm, __shfl_xor(cm, 32, 64));
    cmv[cc] = cm;
  }

  if (lane == 0) wsumLDS[wave] = rowsum;
  if (lane < 16) {
#pragma unroll
    for (int cc = 0; cc < 4; ++cc) colmaxLDS[wave][colc[cc]] = cmv[cc];
#pragma unroll
    for (int r = 0; r < 4; ++r) t12buf[r][wave * 16 + r16] = acc12[r] * sgl;
  }
  __syncthreads();      // the ONLY barrier in the kernel

  if (tid < 64) {   // wave 0
    int col = tid;
    bool valid = pm[i * 65 + 1 + col] == 0;
    float t0 = t12buf[0][col], t1 = t12buf[1][col], t2 = t12buf[2][col], t3 = t12buf[3][col];
    float v = fmaxf(fmaxf(colmaxLDS[0][col], colmaxLDS[1][col]),
                    fmaxf(colmaxLDS[2][col], colmaxLDS[3][col]));
    v = fmaxf(v, fmaxf(fmaxf(t0, t1), fmaxf(t2, t3)));       // full col max (n=0..195)
    float contrib = valid ? v : 0.f;
    float cntv = valid ? 1.f : 0.f;
    float rs0 = valid ? t0 : -__builtin_inff();
    float rs1 = valid ? t1 : -__builtin_inff();
    float rs2 = valid ? t2 : -__builtin_inff();
    float rs3 = valid ? t3 : -__builtin_inff();
#pragma unroll
    for (int off = 1; off < 64; off <<= 1) {
      contrib += __shfl_xor(contrib, off, 64);
      cntv += __shfl_xor(cntv, off, 64);
      rs0 = fmaxf(rs0, __shfl_xor(rs0, off, 64));
      rs1 = fmaxf(rs1, __shfl_xor(rs1, off, 64));
      rs2 = fmaxf(rs2, __shfl_xor(rs2, off, 64));
      rs3 = fmaxf(rs3, __shfl_xor(rs3, off, 64));
    }
    if (tid == 0) {
      lpt[i * 64 + j] = contrib / cntv;
      float wtot = wsumLDS[0] + wsumLDS[1] + wsumLDS[2] + wsumLDS[3];
      lpi[i * 64 + j] = (wtot * 0.0625f + rs0 + rs1 + rs2 + rs3) / 196.f;
    }
  }
}

// ---------------- CE losses + targets ----------------
// out layout: [0] loss | [1..4097) lpi | [4097..8193) lpt | [8193..8257) targets
__global__ __launch_bounds__(64) void ce_kernel(float* __restrict__ out) {
  const int t = threadIdx.x;
  const float* lpi = out + 1;
  const float* lpt = out + 1 + 4096;

  float mx = -__builtin_inff();
  for (int jj = 0; jj < 64; ++jj) mx = fmaxf(mx, lpi[t * 64 + jj]);
  float se = 0.f;
  for (int jj = 0; jj < 64; ++jj) se += __expf(lpi[t * 64 + jj] - mx);
  float ci = (mx + __logf(se)) - lpi[t * 64 + t];

  float mx2 = -__builtin_inff();
  for (int jj = 0; jj < 64; ++jj) mx2 = fmaxf(mx2, lpt[t * 64 + jj]);
  float se2 = 0.f;
  for (int jj = 0; jj < 64; ++jj) se2 += __expf(lpt[t * 64 + jj] - mx2);
  float ct_ = (mx2 + __logf(se2)) - lpt[t * 64 + t];

  float v = ci + ct_;
#pragma unroll
  for (int off = 1; off < 64; off <<= 1) v += __shfl_xor(v, off, 64);
  if (t == 0) out[0] = 0.5f * v / 64.f;
  out[1 + 8192 + t] = (float)t;   // targets = arange(64)
}

extern "C" void kernel_launch(void* const* d_in, const int* in_sizes, int n_in,
                              void* d_out, int out_size, void* d_ws, size_t ws_size,
                              hipStream_t stream) {
  const float* image = (const float*)d_in[0];   // (64,197,768) f32
  const float* text  = (const float*)d_in[1];   // (64,65,768) f32
  const int*   pm    = (const int*)d_in[2];     // (64,65) i32
  const float* ls    = (const float*)d_in[3];   // scalar
  float* out = (float*)d_out;

  _Float16* Apk = (_Float16*)d_ws;              // fragment-tiled image
  _Float16* Bpk = Apk + A_HALFS;                // fragment-tiled text

  repack<<<(AUNITS + TUNITS) / 256, 256, 0, stream>>>(image, text, Apk, Bpk);

  dim3 grid(64, 64);   // x = j (fast): A_i reused by consecutive blocks
  sim_kernel<<<grid, 256, 0, stream>>>(Apk, Bpk, pm, ls, out + 1, out + 1 + 4096);
  ce_kernel<<<1, 64, 0, stream>>>(out);
}

// Round 8
// 188.202 us; speedup vs baseline: 1.3399x; 1.3399x over previous
//
#include <hip/hip_runtime.h>

typedef _Float16 half8 __attribute__((ext_vector_type(8)));
typedef float floatx4 __attribute__((ext_vector_type(4)));
typedef float float4v __attribute__((ext_vector_type(4)));

#define DIM   768
#define NROW  196
#define AUNITS (64 * 13 * 24 * 64)    // 16B units in A'' (fragment-tiled image)
#define TUNITS (64 * 4 * 24 * 64)     // 16B units in B'' (fragment-tiled text)
#define A_HALFS ((size_t)AUNITS * 8)
#define BJ_HALFS (24 * 4 * 64 * 8)    // 49152 halfs per j

__device__ __forceinline__ void gl_lds16(const _Float16* g, _Float16* l) {
  __builtin_amdgcn_global_load_lds(
      (const __attribute__((address_space(1))) unsigned int*)g,
      (__attribute__((address_space(3))) unsigned int*)l, 16, 0, 0);
}

// ---------- repack: f32 -> f16 into MFMA-fragment-tiled layout ----------
// A''[i][tau][s][lane]{8}: lane l holds A_i[n=tau*16+(l&15)][d=s*32+(l>>4)*8..+7]
// B''[j][s][ct][lane]{8}:  lane l holds B_j[m=ct*16+(l&15)][d=s*32+(l>>4)*8..+7]
__global__ __launch_bounds__(256) void repack(const float* __restrict__ img,
                                              const float* __restrict__ txt,
                                              _Float16* __restrict__ Apk,
                                              _Float16* __restrict__ Bpk) {
  int gid = blockIdx.x * 256 + threadIdx.x;
  const float* src;
  _Float16* dst;
  if (gid < AUNITS) {
    int l = gid & 63, g = gid >> 6;
    int s = g % 24; g /= 24;
    int tau = g % 13; int i = g / 13;
    int n = tau * 16 + (l & 15); if (n > 195) n = 195;   // dup-pad rows 196..207
    src = img + (size_t)i * 197 * 768 + (size_t)(n + 1) * 768 + s * 32 + (l >> 4) * 8;
    dst = Apk + (size_t)gid * 8;
  } else {
    int u = gid - AUNITS;
    int l = u & 63, g = u >> 6;
    int ct = g & 3; g >>= 2;
    int s = g % 24; int j = g / 24;
    int m = ct * 16 + (l & 15);
    src = txt + (size_t)j * 65 * 768 + (size_t)(m + 1) * 768 + s * 32 + (l >> 4) * 8;
    dst = Bpk + (size_t)u * 8;
  }
  float4v v0 = *(const float4v*)src;
  float4v v1 = *(const float4v*)(src + 4);
  half8 h;
  h[0] = (_Float16)v0[0]; h[1] = (_Float16)v0[1]; h[2] = (_Float16)v0[2]; h[3] = (_Float16)v0[3];
  h[4] = (_Float16)v1[0]; h[5] = (_Float16)v1[1]; h[6] = (_Float16)v1[2]; h[7] = (_Float16)v1[3];
  *(half8*)dst = h;
}

// ---------- per-(i, jb): computes j0=2jb, j1=2jb+1 sharing the A-stream ----------
// 4 waves; wave w owns row tiles {w, w+4, w+8} plus column-group w of tile 12,
// for BOTH j outputs. A: register depth-2 prefetch. B: chunked DMA dbuf (2x32KB).
__global__ __launch_bounds__(256, 2) void sim_kernel(const _Float16* __restrict__ Apk,
                                                     const _Float16* __restrict__ Bpk,
                                                     const int* __restrict__ pm,
                                                     const float* __restrict__ ls,
                                                     float* __restrict__ lpi,
                                                     float* __restrict__ lpt) {
  __shared__ _Float16 Bsh[32768];           // [buf2][jj2][8192 halfs] = 64 KB

  const int jb = blockIdx.x, i = blockIdx.y;
  const int tid = threadIdx.x;
  const int wave = tid >> 6, lane = tid & 63;
  const int r16 = lane & 15;
  const int lane8 = lane * 8;

  const _Float16* Ai = Apk + (size_t)i * 13 * 24 * 512;
  const _Float16* pA[4];
  pA[0] = Ai + (size_t)(wave)     * 24 * 512 + lane8;
  pA[1] = Ai + (size_t)(wave + 4) * 24 * 512 + lane8;
  pA[2] = Ai + (size_t)(wave + 8) * 24 * 512 + lane8;
  pA[3] = Ai + (size_t)12         * 24 * 512 + lane8;   // tile 12 (all waves)
  const _Float16* Bg = Bpk + (size_t)(2 * jb) * BJ_HALFS;

  // prime: DMA chunk 0 (both j) -> buf 0. 32 x 1KB contiguous instrs, 8/wave.
#pragma unroll
  for (int r8 = 0; r8 < 8; ++r8) {
    int u = wave * 8 + r8;
    int jj = u >> 4, rr = u & 15;
    gl_lds16(Bg + (size_t)jj * BJ_HALFS + rr * 512 + lane8,
             Bsh + jj * 8192 + rr * 512);
  }

  // A pipeline depth 2 (shared by both j outputs)
  half8 af[2][4];
#pragma unroll
  for (int d = 0; d < 2; ++d)
#pragma unroll
    for (int t = 0; t < 4; ++t)
      af[d][t] = *(const half8*)(pA[t] + d * 512);

  floatx4 acc[2][3][4];
  floatx4 acc12[2];
  acc12[0] = (floatx4){0.f, 0.f, 0.f, 0.f};
  acc12[1] = (floatx4){0.f, 0.f, 0.f, 0.f};
#pragma unroll
  for (int jj = 0; jj < 2; ++jj)
#pragma unroll
    for (int t = 0; t < 3; ++t)
#pragma unroll
      for (int cc = 0; cc < 4; ++cc)
        acc[jj][t][cc] = (floatx4){0.f, 0.f, 0.f, 0.f};

#pragma unroll
  for (int c = 0; c < 6; ++c) {
    __syncthreads();                        // drains chunk-c DMA into buf[c&1]
    if (c < 5) {                            // issue chunk c+1 -> buf[(c+1)&1] now;
#pragma unroll                              // it flies during all of chunk c's compute
      for (int r8 = 0; r8 < 8; ++r8) {
        int u = wave * 8 + r8;
        int jj = u >> 4, rr = u & 15;
        gl_lds16(Bg + (size_t)jj * BJ_HALFS + (c + 1) * 8192 + rr * 512 + lane8,
                 Bsh + ((c + 1) & 1) * 16384 + jj * 8192 + rr * 512);
      }
    }
#pragma unroll
    for (int sc = 0; sc < 4; ++sc) {
      const int s = c * 4 + sc;
      const int base = (c & 1) * 16384 + sc * 2048 + lane8;
      half8 b0[4], b1[4];
#pragma unroll
      for (int cc = 0; cc < 4; ++cc) {
        int ct = (wave + cc) & 3;           // rotated: [0] is this wave's own group
        b0[cc] = *(const half8*)(Bsh + base + ct * 512);
        b1[cc] = *(const half8*)(Bsh + base + 8192 + ct * 512);
      }
      half8 a0 = af[s & 1][0], a1 = af[s & 1][1], a2 = af[s & 1][2], a3 = af[s & 1][3];
      if (s < 22) {                         // prefetch K-step s+2
#pragma unroll
        for (int t = 0; t < 4; ++t) af[s & 1][t] = *(const half8*)(pA[t] + (s + 2) * 512);
      }
#pragma unroll
      for (int cc = 0; cc < 4; ++cc) {
        acc[0][0][cc] = __builtin_amdgcn_mfma_f32_16x16x32_f16(a0, b0[cc], acc[0][0][cc], 0, 0, 0);
        acc[0][1][cc] = __builtin_amdgcn_mfma_f32_16x16x32_f16(a1, b0[cc], acc[0][1][cc], 0, 0, 0);
        acc[0][2][cc] = __builtin_amdgcn_mfma_f32_16x16x32_f16(a2, b0[cc], acc[0][2][cc], 0, 0, 0);
        acc[1][0][cc] = __builtin_amdgcn_mfma_f32_16x16x32_f16(a0, b1[cc], acc[1][0][cc], 0, 0, 0);
        acc[1][1][cc] = __builtin_amdgcn_mfma_f32_16x16x32_f16(a1, b1[cc], acc[1][1][cc], 0, 0, 0);
        acc[1][2][cc] = __builtin_amdgcn_mfma_f32_16x16x32_f16(a2, b1[cc], acc[1][2][cc], 0, 0, 0);
      }
      acc12[0] = __builtin_amdgcn_mfma_f32_16x16x32_f16(a3, b0[0], acc12[0], 0, 0, 0);
      acc12[1] = __builtin_amdgcn_mfma_f32_16x16x32_f16(a3, b1[0], acc12[1], 0, 0, 0);
    }
  }

  // ---------------- epilogue (both jj) ----------------
  const float sgl = ls[0];
  // mask depends on i only (reference broadcasts pm over i, not j)
  bool msk[4];
  int colc[4];
#pragma unroll
  for (int cc = 0; cc < 4; ++cc) {
    colc[cc] = ((wave + cc) & 3) * 16 + r16;
    msk[cc] = pm[i * 65 + 1 + colc[cc]] != 0;
  }

  float rowsum[2] = {0.f, 0.f};
  float cmv[2][4];
#pragma unroll
  for (int jj = 0; jj < 2; ++jj) {
    // rows 0..191 row-max over valid m (counted by all 16 r16-lanes)
#pragma unroll
    for (int t = 0; t < 3; ++t) {
#pragma unroll
      for (int r = 0; r < 4; ++r) {
        float rm = -__builtin_inff();
#pragma unroll
        for (int cc = 0; cc < 4; ++cc) {
          float v = acc[jj][t][cc][r] * sgl;
          rm = fmaxf(rm, msk[cc] ? -__builtin_inff() : v);
        }
#pragma unroll
        for (int off = 1; off < 16; off <<= 1)
          rm = fmaxf(rm, __shfl_xor(rm, off, 64));
        rowsum[jj] += rm;
      }
    }
#pragma unroll
    for (int off = 1; off < 64; off <<= 1) rowsum[jj] += __shfl_xor(rowsum[jj], off, 64);

    // per-column max over rows 0..191 (unmasked, per reference max_n)
#pragma unroll
    for (int cc = 0; cc < 4; ++cc) {
      float cm = -__builtin_inff();
#pragma unroll
      for (int t = 0; t < 3; ++t)
#pragma unroll
        for (int r = 0; r < 4; ++r)
          cm = fmaxf(cm, acc[jj][t][cc][r] * sgl);
      cm = fmaxf(cm, __shfl_xor(cm, 16, 64));
      cm = fmaxf(cm, __shfl_xor(cm, 32, 64));
      cmv[jj][cc] = cm;
    }
  }

  __syncthreads();                          // all B reads done -> alias Bsh as scratch
  float* colmaxS = (float*)Bsh;             // [2][4][64]
  float* t12S    = (float*)Bsh + 512;       // [2][4][64]
  float* wsumS   = (float*)Bsh + 1024;      // [2][4]

  if (lane == 0) { wsumS[wave] = rowsum[0]; wsumS[4 + wave] = rowsum[1]; }
  if (lane < 16) {
#pragma unroll
    for (int jj = 0; jj < 2; ++jj) {
#pragma unroll
      for (int cc = 0; cc < 4; ++cc) colmaxS[jj * 256 + wave * 64 + colc[cc]] = cmv[jj][cc];
#pragma unroll
      for (int r = 0; r < 4; ++r) t12S[jj * 256 + r * 64 + wave * 16 + r16] = acc12[jj][r] * sgl;
    }
  }
  __syncthreads();

  if (tid < 128) {   // wave 0 -> jj 0, wave 1 -> jj 1
    const int jj = wave;
    const int col = lane;
    bool valid = pm[i * 65 + 1 + col] == 0;
    const float* cm = colmaxS + jj * 256;
    const float* t12 = t12S + jj * 256;
    float t0 = t12[col], t1 = t12[64 + col], t2 = t12[128 + col], t3 = t12[192 + col];
    float v = fmaxf(fmaxf(cm[col], cm[64 + col]), fmaxf(cm[128 + col], cm[192 + col]));
    v = fmaxf(v, fmaxf(fmaxf(t0, t1), fmaxf(t2, t3)));       // full col max (n=0..195)
    float contrib = valid ? v : 0.f;
    float cntv = valid ? 1.f : 0.f;
    float rs0 = valid ? t0 : -__builtin_inff();
    float rs1 = valid ? t1 : -__builtin_inff();
    float rs2 = valid ? t2 : -__builtin_inff();
    float rs3 = valid ? t3 : -__builtin_inff();
#pragma unroll
    for (int off = 1; off < 64; off <<= 1) {
      contrib += __shfl_xor(contrib, off, 64);
      cntv += __shfl_xor(cntv, off, 64);
      rs0 = fmaxf(rs0, __shfl_xor(rs0, off, 64));
      rs1 = fmaxf(rs1, __shfl_xor(rs1, off, 64));
      rs2 = fmaxf(rs2, __shfl_xor(rs2, off, 64));
      rs3 = fmaxf(rs3, __shfl_xor(rs3, off, 64));
    }
    if (lane == 0) {
      int jout = 2 * jb + jj;
      lpt[i * 64 + jout] = contrib / cntv;
      float wtot = wsumS[jj * 4 + 0] + wsumS[jj * 4 + 1] + wsumS[jj * 4 + 2] + wsumS[jj * 4 + 3];
      lpi[i * 64 + jout] = (wtot * 0.0625f + rs0 + rs1 + rs2 + rs3) / 196.f;
    }
  }
}

// ---------------- CE losses + targets ----------------
// out layout: [0] loss | [1..4097) lpi | [4097..8193) lpt | [8193..8257) targets
__global__ __launch_bounds__(64) void ce_kernel(float* __restrict__ out) {
  const int t = threadIdx.x;
  const float* lpi = out + 1;
  const float* lpt = out + 1 + 4096;

  float mx = -__builtin_inff();
  for (int jj = 0; jj < 64; ++jj) mx = fmaxf(mx, lpi[t * 64 + jj]);
  float se = 0.f;
  for (int jj = 0; jj < 64; ++jj) se += __expf(lpi[t * 64 + jj] - mx);
  float ci = (mx + __logf(se)) - lpi[t * 64 + t];

  float mx2 = -__builtin_inff();
  for (int jj = 0; jj < 64; ++jj) mx2 = fmaxf(mx2, lpt[t * 64 + jj]);
  float se2 = 0.f;
  for (int jj = 0; jj < 64; ++jj) se2 += __expf(lpt[t * 64 + jj] - mx2);
  float ct_ = (mx2 + __logf(se2)) - lpt[t * 64 + t];

  float v = ci + ct_;
#pragma unroll
  for (int off = 1; off < 64; off <<= 1) v += __shfl_xor(v, off, 64);
  if (t == 0) out[0] = 0.5f * v / 64.f;
  out[1 + 8192 + t] = (float)t;   // targets = arange(64)
}

extern "C" void kernel_launch(void* const* d_in, const int* in_sizes, int n_in,
                              void* d_out, int out_size, void* d_ws, size_t ws_size,
                              hipStream_t stream) {
  const float* image = (const float*)d_in[0];   // (64,197,768) f32
  const float* text  = (const float*)d_in[1];   // (64,65,768) f32
  const int*   pm    = (const int*)d_in[2];     // (64,65) i32
  const float* ls    = (const float*)d_in[3];   // scalar
  float* out = (float*)d_out;

  _Float16* Apk = (_Float16*)d_ws;              // fragment-tiled image
  _Float16* Bpk = Apk + A_HALFS;                // fragment-tiled text

  repack<<<(AUNITS + TUNITS) / 256, 256, 0, stream>>>(image, text, Apk, Bpk);

  dim3 grid(32, 64);   // x = jb (fast): A_i stays L2-hot across consecutive blocks
  sim_kernel<<<grid, 256, 0, stream>>>(Apk, Bpk, pm, ls, out + 1, out + 1 + 4096);
  ce_kernel<<<1, 64, 0, stream>>>(out);
}